// Round 3
// baseline (56.633 us; speedup 1.0000x reference)
//
#include <hip/hip_runtime.h>
#include <math.h>

// Problem constants (from reference)
constexpr int NODE_NUM = 1000000;
constexpr int TYPE_NUM = 4;
constexpr int DIM      = 128;
constexpr int K        = 5;
constexpr int M        = 5;
constexpr int B        = 256;
constexpr int LK       = 75;          // L - K
constexpr int NBL      = B * LK;      // 19200 (b,l) pairs
constexpr int PS       = NBL * K;     // 96000  pos_score elems
constexpr int NS       = NBL * K * M; // 480000 neg_score elems

// Output layout (concatenated flat, all float32):
// [0,        PS)            : pos_score
// [PS,       PS+NS)         : neg_score
// [PS+NS,    PS+NS+PS)      : pos_pair_type_out (as float)
// [PS+NS+PS, PS+NS+PS+NS)   : neg_pair_type_out (as float)

// 15 row-pairs per (b,l): pair j covers rows {2j, 2j+1}; row r<5 = pos r, else neg r-5.
// Pipeline: 3 batches of 5 pairs; batch i+1's gathers are in flight while batch i
// computes/reduces/stores. Peak live ev = 2 batches = 40 VGPRs.

template<int J0>
__device__ __forceinline__ void issue_batch(
    const float* __restrict__ node_emb,
    const int* __restrict__ idxs,   // 30 row node ids (wave-uniform, SGPR-resident)
    int half, int hl, float4 ev[5])
{
    #pragma unroll
    for (int j = 0; j < 5; ++j) {
        const int r0 = 2 * (J0 + j), r1 = r0 + 1;
        const int myid = half ? idxs[r1] : idxs[r0];
        ev[j] = *(const float4*)(node_emb + (size_t)myid * DIM + 4 * hl);
    }
}

template<int J0>
__device__ __forceinline__ void compute_batch(
    const float* __restrict__ sig,
    const int* __restrict__ tps,    // 30 row pair-type ids (wave-uniform)
    int half, int hl, const float4& we, const float4 ev[5],
    int idx, float* __restrict__ out)
{
    #pragma unroll
    for (int j = 0; j < 5; ++j) {
        const int r    = 2 * (J0 + j) + half;
        const int mytp = half ? tps[2 * (J0 + j) + 1] : tps[2 * (J0 + j)];
        const float4 sg = *(const float4*)(&sig[mytp * DIM + 4 * hl]);
        float v = we.x * sg.x * ev[j].x + we.y * sg.y * ev[j].y
                + we.z * sg.z * ev[j].z + we.w * sg.w * ev[j].w;
        #pragma unroll
        for (int m2 = 16; m2 >= 1; m2 >>= 1) v += __shfl_xor(v, m2, 64);
        if (hl == 0) {
            if (r < K) {
                out[idx * K + r]           = v;
                out[PS + NS + idx * K + r] = (float)(TYPE_NUM * TYPE_NUM * r + mytp);
            } else {
                const int rr = r - K;           // 0..24
                const int k  = rr / M;          // compile-time per (J0,j,half)
                out[PS + idx * K * M + rr]           = v;
                out[PS + NS + PS + idx * K * M + rr] = (float)(TYPE_NUM * TYPE_NUM * k + mytp);
            }
        }
    }
}

__global__ __launch_bounds__(256, 6) void skipgram_kernel(
    const int*   __restrict__ walk,       // [NBL]
    const int*   __restrict__ pos,        // [NBL*K]
    const int*   __restrict__ neg,        // [NBL*K*M]
    const int*   __restrict__ walk_type,  // [NBL]
    const int*   __restrict__ pos_type,   // [NBL*K]
    const int*   __restrict__ neg_type,   // [NBL*K*M]
    const float* __restrict__ node_emb,   // [NODE_NUM*DIM]
    const float* __restrict__ rel_emb,    // [16*DIM]
    float*       __restrict__ out)
{
    // Stage sigmoid(relationship_embedding) in LDS: 16*128 floats = 8 KB
    __shared__ float sig[TYPE_NUM * TYPE_NUM * DIM];
    const int tid = threadIdx.x;
    for (int i = tid; i < TYPE_NUM * TYPE_NUM * DIM; i += 256) {
        const float x = rel_emb[i];
        sig[i] = 1.0f / (1.0f + expf(-x));
    }
    __syncthreads();

    const int wave = tid >> 6;
    const int lane = tid & 63;
    const int half = lane >> 5;   // 0: even row of pair, 1: odd row
    const int hl   = lane & 31;   // dims 4*hl .. 4*hl+3

    int idx = blockIdx.x * 4 + wave;                 // b*LK + l (wave-uniform)
    idx = __builtin_amdgcn_readfirstlane(idx);       // force scalar indices

    const int wnode = walk[idx];
    const int wt    = walk_type[idx];

    // Row node-ids and pair-type ids for all 30 rows (uniform -> scalar loads)
    int idxs[30], tps[30];
    #pragma unroll
    for (int r = 0; r < 30; ++r) {
        if (r < K) {
            idxs[r] = pos[idx * K + r];
            tps[r]  = TYPE_NUM * wt + pos_type[idx * K + r];
        } else {
            idxs[r] = neg[idx * K * M + r - K];
            tps[r]  = TYPE_NUM * wt + neg_type[idx * K * M + r - K];
        }
    }

    // walk embedding fragment (both halves load the same 16B; HW coalesces)
    const float4 we = *(const float4*)(node_emb + (size_t)wnode * DIM + 4 * hl);

    // Rolling pipeline over 3 batches of 5 pairs
    float4 evA[5], evB[5], evC[5];
    issue_batch<0>(node_emb, idxs, half, hl, evA);
    issue_batch<5>(node_emb, idxs, half, hl, evB);
    compute_batch<0>(sig, tps, half, hl, we, evA, idx, out);
    issue_batch<10>(node_emb, idxs, half, hl, evC);
    compute_batch<5>(sig, tps, half, hl, we, evB, idx, out);
    compute_batch<10>(sig, tps, half, hl, we, evC, idx, out);
}

extern "C" void kernel_launch(void* const* d_in, const int* in_sizes, int n_in,
                              void* d_out, int out_size, void* d_ws, size_t ws_size,
                              hipStream_t stream) {
    const int*   walk      = (const int*)d_in[0];
    const int*   pos       = (const int*)d_in[1];
    const int*   neg       = (const int*)d_in[2];
    const int*   walk_type = (const int*)d_in[3];
    const int*   pos_type  = (const int*)d_in[4];
    const int*   neg_type  = (const int*)d_in[5];
    const float* node_emb  = (const float*)d_in[6];
    const float* rel_emb   = (const float*)d_in[7];
    float* out = (float*)d_out;

    const int blocks = NBL / 4;  // 4 waves per block, one (b,l) per wave
    skipgram_kernel<<<blocks, 256, 0, stream>>>(
        walk, pos, neg, walk_type, pos_type, neg_type, node_emb, rel_emb, out);
}